// Round 7
// baseline (1006.765 us; speedup 1.0000x reference)
//
#include <hip/hip_runtime.h>
#include <hip/hip_bf16.h>

// NetHY: kNN-hypergraph 2-layer conv on MI355X (gfx950)
// R7: gemm1 LDS layout -> kstep-major [ks][256r][16sh] with chunk swizzle
//     h' = h ^ ((row>>2)&1): each 32x32 fragment read is a bijection onto a
//     contiguous 1KB (R2's measured-conflict-free property). Staging applies
//     the inverse permutation on the GLOBAL source (linear LDS dest, rule 21).
//     Keeps R6's lean 2-barrier loop, depth-2 vmcnt(8), 32x32x16 MFMA.
// Workspace requirement: ~208 MB (0xD000000 bytes).

typedef __bf16 bf16x8 __attribute__((ext_vector_type(8)));
typedef float  f32x4  __attribute__((ext_vector_type(4)));
typedef float  f32x16 __attribute__((ext_vector_type(16)));
typedef unsigned short u16x4 __attribute__((ext_vector_type(4)));

#define GLL16(gp, lp) __builtin_amdgcn_global_load_lds( \
    (const __attribute__((address_space(1))) void*)(gp), \
    (__attribute__((address_space(3))) void*)(lp), 16, 0, 0)

__device__ __forceinline__ unsigned short f2bfu(float f) {
    unsigned int u = __float_as_uint(f);
    unsigned int r = (u + 0x7FFFu + ((u >> 16) & 1u)) >> 16;   // RNE, no NaN in data
    return (unsigned short)r;
}
__device__ __forceinline__ float bfu2f(unsigned short s) {
    return __uint_as_float(((unsigned int)s) << 16);
}

// ---------------------------------------------------------------- top-k(8)
__global__ __launch_bounds__(256) void topk8(const float* __restrict__ S,
                                             int* __restrict__ members,
                                             int* __restrict__ deg) {
    __shared__ float sv[2][2048];
    __shared__ int   si[2][2048];
    int row = blockIdx.x, t = threadIdx.x;
    const float* Sr = S + (size_t)row * 4096;
    float v[8]; int ix[8];
#pragma unroll
    for (int i = 0; i < 8; i++) { v[i] = -3.402823466e38f; ix[i] = 0x7FFFFFFF; }
    for (int j = t; j < 4096; j += 256) {
        float x = Sr[j];
        if (x > v[7]) {                    // strict: equal keeps earlier (smaller) index
            v[7] = x; ix[7] = j;
#pragma unroll
            for (int i = 7; i > 0; i--) {
                if (v[i] > v[i-1]) {
                    float tv = v[i]; v[i] = v[i-1]; v[i-1] = tv;
                    int   ti = ix[i]; ix[i] = ix[i-1]; ix[i-1] = ti;
                }
            }
        }
    }
#pragma unroll
    for (int i = 0; i < 8; i++) { sv[0][t*8+i] = v[i]; si[0][t*8+i] = ix[i]; }
    __syncthreads();
    int cur = 0;
    for (int half = 128; half >= 1; half >>= 1) {
        if (t < half) {
            const float* av = &sv[cur][t*8];        const int* ai = &si[cur][t*8];
            const float* bv = &sv[cur][(t+half)*8]; const int* bi = &si[cur][(t+half)*8];
            float* ov = &sv[cur^1][t*8];            int* oi = &si[cur^1][t*8];
            int pa = 0, pb = 0;
#pragma unroll
            for (int r = 0; r < 8; r++) {
                float va = av[pa], vb = bv[pb];
                int   ia = ai[pa], ib = bi[pb];
                bool ta = (va > vb) || (va == vb && ia < ib);
                if (ta) { ov[r] = va; oi[r] = ia; pa++; }
                else    { ov[r] = vb; oi[r] = ib; pb++; }
            }
        }
        __syncthreads();
        cur ^= 1;
    }
    if (t < 8) {
        int idx = si[cur][t];
        members[row*8 + t] = idx;
        atomicAdd(&deg[idx], 1);
    }
}

// ------------------------------------------------------------- CSR helpers
__global__ __launch_bounds__(1024) void scan4096(const int* __restrict__ deg,
                                                 int* __restrict__ offs) {
    __shared__ int ts[1024];
    int t = threadIdx.x;
    int a0 = deg[t*4], a1 = deg[t*4+1], a2 = deg[t*4+2], a3 = deg[t*4+3];
    int s = a0 + a1 + a2 + a3;
    ts[t] = s; __syncthreads();
    for (int off = 1; off < 1024; off <<= 1) {
        int v = (t >= off) ? ts[t - off] : 0;
        __syncthreads();
        ts[t] += v;
        __syncthreads();
    }
    int excl = ts[t] - s;
    offs[t*4]   = excl;
    offs[t*4+1] = excl + a0;
    offs[t*4+2] = excl + a0 + a1;
    offs[t*4+3] = excl + a0 + a1 + a2;
    if (t == 1023) offs[4096] = ts[t];
}

__global__ __launch_bounds__(256) void csrfill(const int* __restrict__ members,
                                               const int* __restrict__ offs,
                                               int* __restrict__ cursor,
                                               int* __restrict__ list) {
    int i = blockIdx.x * 256 + threadIdx.x;   // 32768
    int n = members[i];
    int pos = atomicAdd(&cursor[n], 1);
    list[offs[n] + pos] = i >> 3;             // edge id
}

__global__ __launch_bounds__(256) void csrsort(const int* __restrict__ offs,
                                               const int* __restrict__ deg,
                                               int* __restrict__ list) {
    int n = blockIdx.x * 256 + threadIdx.x;
    if (n >= 4096) return;
    int o = offs[n], d = deg[n];
    for (int i = 1; i < d; i++) {
        int key = list[o+i]; int j = i - 1;
        while (j >= 0 && list[o+j] > key) { list[o+j+1] = list[o+j]; j--; }
        list[o+j+1] = key;
    }
}

// --------------------------------------------------- fp32 -> bf16 hi/lo split
__global__ __launch_bounds__(256) void splitk(const float* __restrict__ in,
                                              unsigned short* __restrict__ hi,
                                              unsigned short* __restrict__ lo,
                                              int n4) {
    int i = blockIdx.x * 256 + threadIdx.x;
    int stride = gridDim.x * 256;
    const float4* in4 = (const float4*)in;
    for (; i < n4; i += stride) {
        float4 v = in4[i];
        float vv[4] = {v.x, v.y, v.z, v.w};
        u16x4 h, l;
#pragma unroll
        for (int j = 0; j < 4; j++) {
            unsigned short hh = f2bfu(vv[j]);
            h[j] = hh;
            l[j] = f2bfu(vv[j] - bfu2f(hh));
        }
        *(u16x4*)(hi + (size_t)i*4) = h;
        *(u16x4*)(lo + (size_t)i*4) = l;
    }
}

// transpose [R][C] fp32 -> [C][R] bf16 hi/lo. grid (C/64, R/64), block 256
__global__ __launch_bounds__(256) void tsplit(const float* __restrict__ in,
                                              unsigned short* __restrict__ oh,
                                              unsigned short* __restrict__ ol,
                                              int R, int C) {
    __shared__ float tile[64][65];
    int c0 = blockIdx.x * 64, r0 = blockIdx.y * 64;
    int tx = threadIdx.x & 63, ty = threadIdx.x >> 6;   // 64 x 4
#pragma unroll
    for (int i = 0; i < 16; i++) {
        int r = i * 4 + ty;
        tile[r][tx] = in[(size_t)(r0 + r) * C + c0 + tx];
    }
    __syncthreads();
#pragma unroll
    for (int i = 0; i < 16; i++) {
        int c = i * 4 + ty;                      // output-local row = input col
        float v = tile[tx][c];
        unsigned short hh = f2bfu(v);
        size_t o = (size_t)(c0 + c) * R + r0 + tx;
        oh[o] = hh;
        ol[o] = f2bfu(v - bfu2f(hh));
    }
}

// --------------------------------------------------------------- GEMM1
// C[4096][4096] = A * B(^T rows), 3-term bf16 hi/lo split, 32x32x16 MFMA.
// 256x256 tile, BK=32, 512 thr (8 waves 2x4), double-buffered 128KB LDS.
// LDS per tensor: [ks][256 rows][16 shorts], chunk h stored at h^((row>>2)&1).
// Each fragment read = bijection onto contiguous 1KB -> conflict-free.
__global__ __launch_bounds__(512, 2) void gemm1(const unsigned short* __restrict__ Ah,
                                                const unsigned short* __restrict__ Al,
                                                const unsigned short* __restrict__ Bh,
                                                const unsigned short* __restrict__ Bl,
                                                float* __restrict__ C) {
    // [buf][tensor: Ah,Al,Bh,Bl][2 ks][256 rows][16 k-shorts] ; 128 KB total
    __shared__ __align__(16) unsigned short sm[2 * 4 * 8192];

    const int t = threadIdx.x, lane = t & 63, wid = t >> 6;
    const int wr = wid >> 2, wc = wid & 3;          // wave grid 2x4
    const int ln31 = lane & 31;

    const int bid = blockIdx.x;                     // 256 = 16x16 tiles
    const int swz = (bid & 7) * 32 + (bid >> 3);    // 32 consecutive per XCD
    const int bm = swz >> 4, bn = swz & 15;

    // ---- staging: wave wid stages kstep-half (wid>>2) of rows (wid&3)*64+[0,64)
    // lane l, instr i: row = (wid&3)*64 + i*32 + (l>>1),
    //                  granule g = (wid>>2)*2 + ((l&1) ^ ((l>>3)&1))
    // LDS dest linear (rule 21): idx = wid*1024 + i*512 + l*8 shorts
    const unsigned stgRow = (unsigned)((wid & 3) * 64 + (lane >> 1));
    const unsigned gsel   = (unsigned)((wid >> 2) * 16 + ((lane & 1) ^ ((lane >> 3) & 1)) * 8);
    const unsigned baseA0 = ((unsigned)(bm * 256) + stgRow) * 4096u + gsel;
    const unsigned baseA1 = baseA0 + 32u * 4096u;
    const unsigned baseB0 = ((unsigned)(bn * 256) + stgRow) * 4096u + gsel;
    const unsigned baseB1 = baseB0 + 32u * 4096u;
    const int dls = wid * 1024;                     // dest shorts (+512 for i=1)

#define STAGE1(kt, buf) {                                              \
    const int bb_ = (buf) * 32768; const unsigned ko_ = (kt) * 32u;    \
    GLL16(Ah + baseA0 + ko_, &sm[bb_ + 0*8192 + dls]);                 \
    GLL16(Ah + baseA1 + ko_, &sm[bb_ + 0*8192 + dls + 512]);           \
    GLL16(Al + baseA0 + ko_, &sm[bb_ + 1*8192 + dls]);                 \
    GLL16(Al + baseA1 + ko_, &sm[bb_ + 1*8192 + dls + 512]);           \
    GLL16(Bh + baseB0 + ko_, &sm[bb_ + 2*8192 + dls]);                 \
    GLL16(Bh + baseB1 + ko_, &sm[bb_ + 2*8192 + dls + 512]);           \
    GLL16(Bl + baseB0 + ko_, &sm[bb_ + 3*8192 + dls]);                 \
    GLL16(Bl + baseB1 + ko_, &sm[bb_ + 3*8192 + dls + 512]); }

    // ---- ds_read side: fragment (m, ks): row = wr*128 + m*32 + ln31,
    // chunk h = lane>>5 stored at slot h ^ ((row>>2)&1) = (lane>>5)^((lane>>2)&1)
    const int hq8   = ((lane >> 5) ^ ((lane >> 2) & 1)) * 8;
    const int abase = (wr * 128 + ln31) * 16 + hq8;   // + m*512 + ks*4096
    const int bbase = (wc * 64  + ln31) * 16 + hq8;   // + n*512 + ks*4096

#define LDF(bb, T, off) (*reinterpret_cast<const bf16x8*>(&sm[(bb) + (T)*8192 + (off)]))

    f32x16 acc[4][2] = {};
    bf16x8 ah0[4], al0[4], ah1[4], al1[4];
    bf16x8 bh0[2], bl0[2], bh1[2], bl1[2];

    STAGE1(0, 0);
    STAGE1(1, 1);

    for (int kt = 0; kt < 128; ++kt) {
        const int bb = (kt & 1) * 32768;
        if (kt < 126) { asm volatile("s_waitcnt vmcnt(8)" ::: "memory"); }
        else          { asm volatile("s_waitcnt vmcnt(0)" ::: "memory"); }
        __builtin_amdgcn_s_barrier();

        // k0 fragments first (gates first MFMA cluster), then k1 (overlaps)
#pragma unroll
        for (int m = 0; m < 4; m++) { ah0[m] = LDF(bb, 0, abase + m*512);
                                      al0[m] = LDF(bb, 1, abase + m*512); }
#pragma unroll
        for (int n = 0; n < 2; n++) { bh0[n] = LDF(bb, 2, bbase + n*512);
                                      bl0[n] = LDF(bb, 3, bbase + n*512); }
#pragma unroll
        for (int m = 0; m < 4; m++) { ah1[m] = LDF(bb, 0, abase + m*512 + 4096);
                                      al1[m] = LDF(bb, 1, abase + m*512 + 4096); }
#pragma unroll
        for (int n = 0; n < 2; n++) { bh1[n] = LDF(bb, 2, bbase + n*512 + 4096);
                                      bl1[n] = LDF(bb, 3, bbase + n*512 + 4096); }

        // MFMA k-step 0 (compiler gates on k0 reads; k1 reads still in flight)
        __builtin_amdgcn_s_setprio(1);
#pragma unroll
        for (int m = 0; m < 4; m++)
#pragma unroll
            for (int n = 0; n < 2; n++) {
                acc[m][n] = __builtin_amdgcn_mfma_f32_32x32x16_bf16(ah0[m], bh0[n], acc[m][n], 0, 0, 0);
                acc[m][n] = __builtin_amdgcn_mfma_f32_32x32x16_bf16(ah0[m], bl0[n], acc[m][n], 0, 0, 0);
                acc[m][n] = __builtin_amdgcn_mfma_f32_32x32x16_bf16(al0[m], bh0[n], acc[m][n], 0, 0, 0);
            }
        // MFMA k-step 1
#pragma unroll
        for (int m = 0; m < 4; m++)
#pragma unroll
            for (int n = 0; n < 2; n++) {
                acc[m][n] = __builtin_amdgcn_mfma_f32_32x32x16_bf16(ah1[m], bh1[n], acc[m][n], 0, 0, 0);
                acc[m][n] = __builtin_amdgcn_mfma_f32_32x32x16_bf16(ah1[m], bl1[n], acc[m][n], 0, 0, 0);
                acc[m][n] = __builtin_amdgcn_mfma_f32_32x32x16_bf16(al1[m], bh1[n], acc[m][n], 0, 0, 0);
            }
        __builtin_amdgcn_s_setprio(0);

        // all our ds_reads of this buffer complete, then block-wide release
        asm volatile("s_waitcnt lgkmcnt(0)" ::: "memory");
        __builtin_amdgcn_s_barrier();

        // depth-2 prefetch into the buffer just freed
        if (kt + 2 < 128) STAGE1(kt + 2, kt & 1);
    }

    // ---- epilogue: C/D 32x32 layout col=lane&31, row=(j&3)+8*(j>>2)+4*(lane>>5)
    const int rsel = 4 * (lane >> 5);
#pragma unroll
    for (int m = 0; m < 4; m++) {
#pragma unroll
        for (int n = 0; n < 2; n++) {
            int cb = bn * 256 + wc * 64 + n * 32 + ln31;
            int rb = bm * 256 + wr * 128 + m * 32 + rsel;
#pragma unroll
            for (int j = 0; j < 16; j++) {
                int row = rb + (j & 3) + 8 * (j >> 2);
                C[(size_t)row * 4096 + cb] = acc[m][n][j];
            }
        }
    }
#undef STAGE1
#undef LDF
}

// -------------------------------------------------- conv1 aggregation
__global__ __launch_bounds__(256) void edgefeat1(const float* __restrict__ xw,
                                                 const int* __restrict__ members,
                                                 float* __restrict__ ef) {
    int e = blockIdx.x, t = threadIdx.x;
    int m[8];
#pragma unroll
    for (int k = 0; k < 8; k++) m[k] = members[e*8 + k];
#pragma unroll
    for (int it = 0; it < 4; ++it) {
        int c4 = t + it * 256;
        float4 s = {0.f, 0.f, 0.f, 0.f};
#pragma unroll
        for (int k = 0; k < 8; k++) {
            float4 v = *(const float4*)(xw + (size_t)m[k]*4096 + (size_t)c4*4);
            s.x += v.x; s.y += v.y; s.z += v.z; s.w += v.w;
        }
        s.x *= 0.125f; s.y *= 0.125f; s.z *= 0.125f; s.w *= 0.125f;
        *(float4*)(ef + (size_t)e*4096 + (size_t)c4*4) = s;
    }
}

__global__ __launch_bounds__(256) void agg1(const float* __restrict__ ef,
                                            const int* __restrict__ offs,
                                            const int* __restrict__ deg,
                                            const int* __restrict__ list,
                                            const float* __restrict__ b1,
                                            unsigned short* __restrict__ hHi,
                                            unsigned short* __restrict__ hLo) {
    int n = blockIdx.x, t = threadIdx.x;
    int d = deg[n], o = offs[n];
    float inv = d > 0 ? 1.0f / (float)d : 0.0f;
#pragma unroll
    for (int it = 0; it < 4; ++it) {
        int c4 = t + it * 256;
        float4 s = {0.f, 0.f, 0.f, 0.f};
        for (int q = 0; q < d; q++) {
            int e = list[o + q];
            float4 v = *(const float4*)(ef + (size_t)e*4096 + (size_t)c4*4);
            s.x += v.x; s.y += v.y; s.z += v.z; s.w += v.w;
        }
        float4 b = *(const float4*)(b1 + (size_t)c4*4);
        float r[4];
        r[0] = fmaxf(s.x * inv + b.x, 0.f);
        r[1] = fmaxf(s.y * inv + b.y, 0.f);
        r[2] = fmaxf(s.z * inv + b.z, 0.f);
        r[3] = fmaxf(s.w * inv + b.w, 0.f);
        u16x4 h, l;
#pragma unroll
        for (int j = 0; j < 4; j++) {
            unsigned short hh = f2bfu(r[j]);
            h[j] = hh;
            l[j] = f2bfu(r[j] - bfu2f(hh));
        }
        size_t off = (size_t)n*4096 + (size_t)c4*4;
        *(u16x4*)(hHi + off) = h;
        *(u16x4*)(hLo + off) = l;
    }
}

// --------------------------------------------------------------- GEMM2
// gpart[ks][4096][64] partial of h @ w2 ; 64x64 tile, BK=32, K split 8-way.
__global__ __launch_bounds__(256) void gemm2(const unsigned short* __restrict__ Ah,
                                             const unsigned short* __restrict__ Al,
                                             const unsigned short* __restrict__ Bh,
                                             const unsigned short* __restrict__ Bl,
                                             float* __restrict__ gpart) {
    __shared__ __align__(16) unsigned short sAh[64*32], sAl[64*32];
    __shared__ __align__(16) unsigned short sBh[64*32], sBl[64*32];
    int bm = blockIdx.x;            // 64
    int ks = blockIdx.y;            // 8 -> K range 512
    int t = threadIdx.x, lane = t & 63, wid = t >> 6;
    int wr = wid >> 1, wc = wid & 1;
    int ln15 = lane & 15, kq = (lane >> 4) * 8;
    int r = t >> 2, kk = (t & 3) * 8;
    size_t aOff = (size_t)(bm*64 + r) * 4096 + ks * 512 + kk;
    size_t bOff = (size_t)r * 4096 + ks * 512 + kk;   // w2t row r (< 64)
    f32x4 acc[2][2] = {};

    for (int kt = 0; kt < 16; ++kt) {
        int ko = kt * 32;
        GLL16(Ah + aOff + ko, sAh + (size_t)t*8);
        GLL16(Al + aOff + ko, sAl + (size_t)t*8);
        GLL16(Bh + bOff + ko, sBh + (size_t)t*8);
        GLL16(Bl + bOff + ko, sBl + (size_t)t*8);
        asm volatile("s_waitcnt vmcnt(0)" ::: "memory");
        __syncthreads();

        bf16x8 ah[2], al[2], bh[2], bl[2];
#pragma unroll
        for (int m = 0; m < 2; m++) {
            int ro = (wr*32 + m*16 + ln15) * 32 + kq;
            ah[m] = *reinterpret_cast<const bf16x8*>(sAh + ro);
            al[m] = *reinterpret_cast<const bf16x8*>(sAl + ro);
        }
#pragma unroll
        for (int n = 0; n < 2; n++) {
            int ro = (wc*32 + n*16 + ln15) * 32 + kq;
            bh[n] = *reinterpret_cast<const bf16x8*>(sBh + ro);
            bl[n] = *reinterpret_cast<const bf16x8*>(sBl + ro);
        }
#pragma unroll
        for (int m = 0; m < 2; m++)
#pragma unroll
            for (int n = 0; n < 2; n++) {
                acc[m][n] = __builtin_amdgcn_mfma_f32_16x16x32_bf16(ah[m], bh[n], acc[m][n], 0, 0, 0);
                acc[m][n] = __builtin_amdgcn_mfma_f32_16x16x32_bf16(ah[m], bl[n], acc[m][n], 0, 0, 0);
                acc[m][n] = __builtin_amdgcn_mfma_f32_16x16x32_bf16(al[m], bh[n], acc[m][n], 0, 0, 0);
            }
        __syncthreads();
    }

    float* outp = gpart + (size_t)ks * (4096 * 64);
#pragma unroll
    for (int m = 0; m < 2; m++) {
        int rb = bm*64 + wr*32 + m*16 + (lane >> 4) * 4;
#pragma unroll
        for (int n = 0; n < 2; n++) {
            int cb = wc*32 + n*16 + ln15;
#pragma unroll
            for (int j = 0; j < 4; j++)
                outp[(size_t)(rb + j) * 64 + cb] = acc[m][n][j];
        }
    }
}

// -------------------------------------------------- conv2 aggregation + tanh
__global__ __launch_bounds__(256) void ef2k(const float* __restrict__ gpart,
                                            const int* __restrict__ members,
                                            float* __restrict__ ef2) {
    int e = blockIdx.x * 4 + (threadIdx.x >> 6);
    int c = threadIdx.x & 63;
    float s = 0.f;
#pragma unroll
    for (int k = 0; k < 8; k++) {
        int m = members[e*8 + k];
        float g = 0.f;
#pragma unroll
        for (int p = 0; p < 8; p++) g += gpart[(size_t)p * (4096*64) + (size_t)m*64 + c];
        s += g;
    }
    ef2[e*64 + c] = s * 0.125f;
}

__global__ __launch_bounds__(256) void agg2k(const float* __restrict__ ef2,
                                             const int* __restrict__ offs,
                                             const int* __restrict__ deg,
                                             const int* __restrict__ list,
                                             const float* __restrict__ b2,
                                             float* __restrict__ out) {
    int n = blockIdx.x * 4 + (threadIdx.x >> 6);
    int c = threadIdx.x & 63;
    int d = deg[n], o = offs[n];
    float inv = d > 0 ? 1.0f / (float)d : 0.0f;
    float s = 0.f;
    for (int q = 0; q < d; q++) s += ef2[list[o + q] * 64 + c];
    out[(size_t)n*64 + c] = tanhf(s * inv + b2[c]);
}

// ------------------------------------------------------------------ launcher
extern "C" void kernel_launch(void* const* d_in, const int* in_sizes, int n_in,
                              void* d_out, int out_size, void* d_ws, size_t ws_size,
                              hipStream_t stream) {
    const float* x  = (const float*)d_in[0];
    const float* S  = (const float*)d_in[1];
    const float* w1 = (const float*)d_in[2];
    const float* b1 = (const float*)d_in[3];
    const float* w2 = (const float*)d_in[4];
    const float* b2 = (const float*)d_in[5];
    float* out = (float*)d_out;

    char* p = (char*)d_ws;
    int* members = (int*)(p);                         // 128 KB
    int* deg     = (int*)(p + 0x020000);              // 16 KB
    int* cursor  = (int*)(p + 0x024000);              // 16 KB
    int* offs    = (int*)(p + 0x028000);              // 16.4 KB
    int* list    = (int*)(p + 0x030000);              // 128 KB
    unsigned short* w2t_hi = (unsigned short*)(p + 0x050000);  // 512 KB
    unsigned short* w2t_lo = (unsigned short*)(p + 0x0D0000);  // 512 KB
    float* ef2b    = (float*)(p + 0x150000);          // 1 MB
    float* gpart   = (float*)(p + 0x400000);          // 8 MB
    unsigned short* x_hi   = (unsigned short*)(p + 0x1000000); // 32 MB
    unsigned short* x_lo   = x_hi   + (1u << 24);
    unsigned short* w1t_hi = x_lo   + (1u << 24);
    unsigned short* w1t_lo = w1t_hi + (1u << 24);
    float* xw      = (float*)(w1t_lo + (1u << 24));   // 64 MB -> total 0xD000000 (~208 MB)
    float* ef1     = (float*)w1t_hi;                  // reuse after GEMM1
    unsigned short* h_hi = x_hi;                      // reuse after GEMM1
    unsigned short* h_lo = x_lo;

    hipMemsetAsync(p + 0x020000, 0, 0x8000, stream);  // zero deg + cursor

    topk8   <<<4096, 256, 0, stream>>>(S, members, deg);
    scan4096<<<1, 1024, 0, stream>>>(deg, offs);
    csrfill <<<128, 256, 0, stream>>>(members, offs, cursor, list);
    csrsort <<<16, 256, 0, stream>>>(offs, deg, list);

    splitk  <<<4096, 256, 0, stream>>>(x, x_hi, x_lo, 4194304);
    tsplit  <<<dim3(64, 64), 256, 0, stream>>>(w1, w1t_hi, w1t_lo, 4096, 4096);
    tsplit  <<<dim3(1, 64),  256, 0, stream>>>(w2, w2t_hi, w2t_lo, 4096, 64);

    gemm1   <<<256, 512, 0, stream>>>(x_hi, x_lo, w1t_hi, w1t_lo, xw);

    edgefeat1<<<4096, 256, 0, stream>>>(xw, members, ef1);
    agg1    <<<4096, 256, 0, stream>>>(ef1, offs, deg, list, b1, h_hi, h_lo);

    gemm2   <<<dim3(64, 8), 256, 0, stream>>>(h_hi, h_lo, w2t_hi, w2t_lo, gpart);
    ef2k    <<<1024, 256, 0, stream>>>(gpart, members, ef2b);
    agg2k   <<<1024, 256, 0, stream>>>(ef2b, offs, deg, list, b2, out);
}

// Round 8
// 864.796 us; speedup vs baseline: 1.1642x; 1.1642x over previous
//
#include <hip/hip_runtime.h>
#include <hip/hip_bf16.h>

// NetHY: kNN-hypergraph 2-layer conv on MI355X (gfx950)
// R8: re-bank measured optimum. gemm1 = R2 verbatim (373.5 us, 0 bank
//     conflicts, MfmaUtil 49%): 256x256 tile, BK=32, 16x16x32 MFMA, 4-phase
//     schedule, depth-2 vmcnt(8), verified staging/read swizzle involution.
//     Tail = R6's (64x64 tsplit, 479.8 us). No new variables this round.
// Workspace requirement: ~208 MB (0xD000000 bytes).

typedef __bf16 bf16x8 __attribute__((ext_vector_type(8)));
typedef float  f32x4  __attribute__((ext_vector_type(4)));
typedef unsigned short u16x4 __attribute__((ext_vector_type(4)));

#define GLL16(gp, lp) __builtin_amdgcn_global_load_lds( \
    (const __attribute__((address_space(1))) void*)(gp), \
    (__attribute__((address_space(3))) void*)(lp), 16, 0, 0)

__device__ __forceinline__ unsigned short f2bfu(float f) {
    unsigned int u = __float_as_uint(f);
    unsigned int r = (u + 0x7FFFu + ((u >> 16) & 1u)) >> 16;   // RNE, no NaN in data
    return (unsigned short)r;
}
__device__ __forceinline__ float bfu2f(unsigned short s) {
    return __uint_as_float(((unsigned int)s) << 16);
}

// ---------------------------------------------------------------- top-k(8)
__global__ __launch_bounds__(256) void topk8(const float* __restrict__ S,
                                             int* __restrict__ members,
                                             int* __restrict__ deg) {
    __shared__ float sv[2][2048];
    __shared__ int   si[2][2048];
    int row = blockIdx.x, t = threadIdx.x;
    const float* Sr = S + (size_t)row * 4096;
    float v[8]; int ix[8];
#pragma unroll
    for (int i = 0; i < 8; i++) { v[i] = -3.402823466e38f; ix[i] = 0x7FFFFFFF; }
    for (int j = t; j < 4096; j += 256) {
        float x = Sr[j];
        if (x > v[7]) {                    // strict: equal keeps earlier (smaller) index
            v[7] = x; ix[7] = j;
#pragma unroll
            for (int i = 7; i > 0; i--) {
                if (v[i] > v[i-1]) {
                    float tv = v[i]; v[i] = v[i-1]; v[i-1] = tv;
                    int   ti = ix[i]; ix[i] = ix[i-1]; ix[i-1] = ti;
                }
            }
        }
    }
#pragma unroll
    for (int i = 0; i < 8; i++) { sv[0][t*8+i] = v[i]; si[0][t*8+i] = ix[i]; }
    __syncthreads();
    int cur = 0;
    for (int half = 128; half >= 1; half >>= 1) {
        if (t < half) {
            const float* av = &sv[cur][t*8];        const int* ai = &si[cur][t*8];
            const float* bv = &sv[cur][(t+half)*8]; const int* bi = &si[cur][(t+half)*8];
            float* ov = &sv[cur^1][t*8];            int* oi = &si[cur^1][t*8];
            int pa = 0, pb = 0;
#pragma unroll
            for (int r = 0; r < 8; r++) {
                float va = av[pa], vb = bv[pb];
                int   ia = ai[pa], ib = bi[pb];
                bool ta = (va > vb) || (va == vb && ia < ib);
                if (ta) { ov[r] = va; oi[r] = ia; pa++; }
                else    { ov[r] = vb; oi[r] = ib; pb++; }
            }
        }
        __syncthreads();
        cur ^= 1;
    }
    if (t < 8) {
        int idx = si[cur][t];
        members[row*8 + t] = idx;
        atomicAdd(&deg[idx], 1);
    }
}

// ------------------------------------------------------------- CSR helpers
__global__ __launch_bounds__(1024) void scan4096(const int* __restrict__ deg,
                                                 int* __restrict__ offs) {
    __shared__ int ts[1024];
    int t = threadIdx.x;
    int a0 = deg[t*4], a1 = deg[t*4+1], a2 = deg[t*4+2], a3 = deg[t*4+3];
    int s = a0 + a1 + a2 + a3;
    ts[t] = s; __syncthreads();
    for (int off = 1; off < 1024; off <<= 1) {
        int v = (t >= off) ? ts[t - off] : 0;
        __syncthreads();
        ts[t] += v;
        __syncthreads();
    }
    int excl = ts[t] - s;
    offs[t*4]   = excl;
    offs[t*4+1] = excl + a0;
    offs[t*4+2] = excl + a0 + a1;
    offs[t*4+3] = excl + a0 + a1 + a2;
    if (t == 1023) offs[4096] = ts[t];
}

__global__ __launch_bounds__(256) void csrfill(const int* __restrict__ members,
                                               const int* __restrict__ offs,
                                               int* __restrict__ cursor,
                                               int* __restrict__ list) {
    int i = blockIdx.x * 256 + threadIdx.x;   // 32768
    int n = members[i];
    int pos = atomicAdd(&cursor[n], 1);
    list[offs[n] + pos] = i >> 3;             // edge id
}

__global__ __launch_bounds__(256) void csrsort(const int* __restrict__ offs,
                                               const int* __restrict__ deg,
                                               int* __restrict__ list) {
    int n = blockIdx.x * 256 + threadIdx.x;
    if (n >= 4096) return;
    int o = offs[n], d = deg[n];
    for (int i = 1; i < d; i++) {
        int key = list[o+i]; int j = i - 1;
        while (j >= 0 && list[o+j] > key) { list[o+j+1] = list[o+j]; j--; }
        list[o+j+1] = key;
    }
}

// --------------------------------------------------- fp32 -> bf16 hi/lo split
__global__ __launch_bounds__(256) void splitk(const float* __restrict__ in,
                                              unsigned short* __restrict__ hi,
                                              unsigned short* __restrict__ lo,
                                              int n4) {
    int i = blockIdx.x * 256 + threadIdx.x;
    int stride = gridDim.x * 256;
    const float4* in4 = (const float4*)in;
    for (; i < n4; i += stride) {
        float4 v = in4[i];
        float vv[4] = {v.x, v.y, v.z, v.w};
        u16x4 h, l;
#pragma unroll
        for (int j = 0; j < 4; j++) {
            unsigned short hh = f2bfu(vv[j]);
            h[j] = hh;
            l[j] = f2bfu(vv[j] - bfu2f(hh));
        }
        *(u16x4*)(hi + (size_t)i*4) = h;
        *(u16x4*)(lo + (size_t)i*4) = l;
    }
}

// transpose [R][C] fp32 -> [C][R] bf16 hi/lo. grid (C/64, R/64), block 256
__global__ __launch_bounds__(256) void tsplit(const float* __restrict__ in,
                                              unsigned short* __restrict__ oh,
                                              unsigned short* __restrict__ ol,
                                              int R, int C) {
    __shared__ float tile[64][65];
    int c0 = blockIdx.x * 64, r0 = blockIdx.y * 64;
    int tx = threadIdx.x & 63, ty = threadIdx.x >> 6;   // 64 x 4
#pragma unroll
    for (int i = 0; i < 16; i++) {
        int r = i * 4 + ty;
        tile[r][tx] = in[(size_t)(r0 + r) * C + c0 + tx];
    }
    __syncthreads();
#pragma unroll
    for (int i = 0; i < 16; i++) {
        int c = i * 4 + ty;                      // output-local row = input col
        float v = tile[tx][c];
        unsigned short hh = f2bfu(v);
        size_t o = (size_t)(c0 + c) * R + r0 + tx;
        oh[o] = hh;
        ol[o] = f2bfu(v - bfu2f(hh));
    }
}

// --------------------------------------------------------------- GEMM1
// C[4096][4096] = A * B^T-rows, 3-term bf16 hi/lo split.  [R2 verbatim]
// 256x256 tile, BK=32, 512 thr (8 waves 2x4), double-buffered 128KB LDS,
// 4-phase interleave per K-tile, depth-2 counted vmcnt, XOR LDS swizzle.
__global__ __launch_bounds__(512, 2) void gemm1(const unsigned short* __restrict__ Ah,
                                                const unsigned short* __restrict__ Al,
                                                const unsigned short* __restrict__ Bh,
                                                const unsigned short* __restrict__ Bl,
                                                float* __restrict__ C) {
    // [buf][tensor: Ah,Al,Bh,Bl][256 rows][32 k] shorts ; 128 KB total
    __shared__ __align__(16) unsigned short sm[2 * 4 * 8192];

    const int t = threadIdx.x, lane = t & 63, wid = t >> 6;
    const int wr = wid >> 2, wc = wid & 3;          // wave grid 2x4
    const int ln15 = lane & 15;

    const int bid = blockIdx.x;                     // 256 = 16x16 tiles
    const int swz = (bid & 7) * 32 + (bid >> 3);    // 32 consecutive per XCD
    const int bm = swz >> 4, bn = swz & 15;

    // ---- staging: wave wid stages chunks {2wid, 2wid+1} (16 rows x 32k each)
    // global k-chunk pre-swizzled per lane (involution matches the read side)
    const int kc8 = (((lane & 3) ^ ((lane >> 3) & 3))) * 8;
    const unsigned rA0 = (unsigned)(bm * 256 + wid * 32 + (lane >> 2));
    const unsigned rB0 = (unsigned)(bn * 256 + wid * 32 + (lane >> 2));
    const unsigned oA0 = rA0 * 4096u + (unsigned)kc8, oA1 = oA0 + 16u * 4096u;
    const unsigned oB0 = rB0 * 4096u + (unsigned)kc8, oB1 = oB0 + 16u * 4096u;
    const int dls = wid * 1024;                     // chunk c0 dst (shorts)

#define STAGE1(kt, buf) {                                              \
    const int bb_ = (buf) * 32768; const unsigned ko_ = (kt) * 32u;    \
    GLL16(Ah + oA0 + ko_, &sm[bb_ + 0*8192 + dls]);                    \
    GLL16(Ah + oA1 + ko_, &sm[bb_ + 0*8192 + dls + 512]);              \
    GLL16(Al + oA0 + ko_, &sm[bb_ + 1*8192 + dls]);                    \
    GLL16(Al + oA1 + ko_, &sm[bb_ + 1*8192 + dls + 512]);              \
    GLL16(Bh + oB0 + ko_, &sm[bb_ + 2*8192 + dls]);                    \
    GLL16(Bh + oB1 + ko_, &sm[bb_ + 2*8192 + dls + 512]);              \
    GLL16(Bl + oB0 + ko_, &sm[bb_ + 3*8192 + dls]);                    \
    GLL16(Bl + oB1 + ko_, &sm[bb_ + 3*8192 + dls + 512]); }

    // ---- ds_read side: swizzled slot, lane-constant
    const int soff = ((lane >> 4) ^ ((lane >> 1) & 3)) * 8;  // shorts
    const int arow = (wr * 128 + ln15) * 32 + soff;
    const int brow = (wc * 64  + ln15) * 32 + soff;

#define LDF(bb, T, base, idx) \
    (*reinterpret_cast<const bf16x8*>(&sm[(bb) + (T)*8192 + (base) + (idx)*512]))

    f32x4 acc[8][4] = {};
    bf16x8 ah[4], al[4], bh[4], bl[4];

    STAGE1(0, 0);
    STAGE1(1, 1);

    for (int kt = 0; kt < 128; ++kt) {
        const int bb = (kt & 1) * 32768;
        if (kt < 127) { asm volatile("s_waitcnt vmcnt(8)" ::: "memory"); }
        else          { asm volatile("s_waitcnt vmcnt(0)" ::: "memory"); }
        __builtin_amdgcn_s_barrier();

        // ---- phase 0: read a[0-3], b[0-1]; mfma m0-3 x n0-1
#pragma unroll
        for (int m = 0; m < 4; m++) { ah[m] = LDF(bb, 0, arow, m); al[m] = LDF(bb, 1, arow, m); }
#pragma unroll
        for (int n = 0; n < 2; n++) { bh[n] = LDF(bb, 2, brow, n); bl[n] = LDF(bb, 3, brow, n); }
        __builtin_amdgcn_s_barrier();
        asm volatile("s_waitcnt lgkmcnt(0)" ::: "memory");
        __builtin_amdgcn_sched_barrier(0);
        __builtin_amdgcn_s_setprio(1);
#pragma unroll
        for (int m = 0; m < 4; m++)
#pragma unroll
            for (int n = 0; n < 2; n++) {
                acc[m][n] = __builtin_amdgcn_mfma_f32_16x16x32_bf16(ah[m], bh[n], acc[m][n], 0, 0, 0);
                acc[m][n] = __builtin_amdgcn_mfma_f32_16x16x32_bf16(ah[m], bl[n], acc[m][n], 0, 0, 0);
                acc[m][n] = __builtin_amdgcn_mfma_f32_16x16x32_bf16(al[m], bh[n], acc[m][n], 0, 0, 0);
            }
        __builtin_amdgcn_s_setprio(0);
        __builtin_amdgcn_s_barrier();

        // ---- phase 1: read b[2-3]; mfma m0-3 x n2-3
#pragma unroll
        for (int n = 2; n < 4; n++) { bh[n] = LDF(bb, 2, brow, n); bl[n] = LDF(bb, 3, brow, n); }
        __builtin_amdgcn_s_barrier();
        asm volatile("s_waitcnt lgkmcnt(0)" ::: "memory");
        __builtin_amdgcn_sched_barrier(0);
        __builtin_amdgcn_s_setprio(1);
#pragma unroll
        for (int m = 0; m < 4; m++)
#pragma unroll
            for (int n = 2; n < 4; n++) {
                acc[m][n] = __builtin_amdgcn_mfma_f32_16x16x32_bf16(ah[m], bh[n], acc[m][n], 0, 0, 0);
                acc[m][n] = __builtin_amdgcn_mfma_f32_16x16x32_bf16(ah[m], bl[n], acc[m][n], 0, 0, 0);
                acc[m][n] = __builtin_amdgcn_mfma_f32_16x16x32_bf16(al[m], bh[n], acc[m][n], 0, 0, 0);
            }
        __builtin_amdgcn_s_setprio(0);
        __builtin_amdgcn_s_barrier();

        // ---- phase 2: read a[4-7]; mfma m4-7 x n0-1
#pragma unroll
        for (int m = 0; m < 4; m++) { ah[m] = LDF(bb, 0, arow, m + 4); al[m] = LDF(bb, 1, arow, m + 4); }
        __builtin_amdgcn_s_barrier();
        asm volatile("s_waitcnt lgkmcnt(0)" ::: "memory");
        __builtin_amdgcn_sched_barrier(0);
        __builtin_amdgcn_s_setprio(1);
#pragma unroll
        for (int m = 0; m < 4; m++)
#pragma unroll
            for (int n = 0; n < 2; n++) {
                acc[m+4][n] = __builtin_amdgcn_mfma_f32_16x16x32_bf16(ah[m], bh[n], acc[m+4][n], 0, 0, 0);
                acc[m+4][n] = __builtin_amdgcn_mfma_f32_16x16x32_bf16(ah[m], bl[n], acc[m+4][n], 0, 0, 0);
                acc[m+4][n] = __builtin_amdgcn_mfma_f32_16x16x32_bf16(al[m], bh[n], acc[m+4][n], 0, 0, 0);
            }
        __builtin_amdgcn_s_setprio(0);
        __builtin_amdgcn_s_barrier();

        // ---- phase 3: mfma m4-7 x n2-3 (register-only)
        __builtin_amdgcn_s_setprio(1);
#pragma unroll
        for (int m = 0; m < 4; m++)
#pragma unroll
            for (int n = 2; n < 4; n++) {
                acc[m+4][n] = __builtin_amdgcn_mfma_f32_16x16x32_bf16(ah[m], bh[n], acc[m+4][n], 0, 0, 0);
                acc[m+4][n] = __builtin_amdgcn_mfma_f32_16x16x32_bf16(ah[m], bl[n], acc[m+4][n], 0, 0, 0);
                acc[m+4][n] = __builtin_amdgcn_mfma_f32_16x16x32_bf16(al[m], bh[n], acc[m+4][n], 0, 0, 0);
            }
        __builtin_amdgcn_s_setprio(0);

        // ---- depth-2 prefetch: stage tile kt+2 into the buffer just freed
        if (kt + 2 < 128) STAGE1(kt + 2, kt & 1);
    }

    // ---- epilogue
#pragma unroll
    for (int m = 0; m < 8; m++) {
        int rb = bm * 256 + wr * 128 + m * 16 + (lane >> 4) * 4;
#pragma unroll
        for (int n = 0; n < 4; n++) {
            int cb = bn * 256 + wc * 64 + n * 16 + ln15;
#pragma unroll
            for (int j = 0; j < 4; j++)
                C[(size_t)(rb + j) * 4096 + cb] = acc[m][n][j];
        }
    }
#undef STAGE1
#undef LDF
}

// -------------------------------------------------- conv1 aggregation
__global__ __launch_bounds__(256) void edgefeat1(const float* __restrict__ xw,
                                                 const int* __restrict__ members,
                                                 float* __restrict__ ef) {
    int e = blockIdx.x, t = threadIdx.x;
    int m[8];
#pragma unroll
    for (int k = 0; k < 8; k++) m[k] = members[e*8 + k];
#pragma unroll
    for (int it = 0; it < 4; ++it) {
        int c4 = t + it * 256;
        float4 s = {0.f, 0.f, 0.f, 0.f};
#pragma unroll
        for (int k = 0; k < 8; k++) {
            float4 v = *(const float4*)(xw + (size_t)m[k]*4096 + (size_t)c4*4);
            s.x += v.x; s.y += v.y; s.z += v.z; s.w += v.w;
        }
        s.x *= 0.125f; s.y *= 0.125f; s.z *= 0.125f; s.w *= 0.125f;
        *(float4*)(ef + (size_t)e*4096 + (size_t)c4*4) = s;
    }
}

__global__ __launch_bounds__(256) void agg1(const float* __restrict__ ef,
                                            const int* __restrict__ offs,
                                            const int* __restrict__ deg,
                                            const int* __restrict__ list,
                                            const float* __restrict__ b1,
                                            unsigned short* __restrict__ hHi,
                                            unsigned short* __restrict__ hLo) {
    int n = blockIdx.x, t = threadIdx.x;
    int d = deg[n], o = offs[n];
    float inv = d > 0 ? 1.0f / (float)d : 0.0f;
#pragma unroll
    for (int it = 0; it < 4; ++it) {
        int c4 = t + it * 256;
        float4 s = {0.f, 0.f, 0.f, 0.f};
        for (int q = 0; q < d; q++) {
            int e = list[o + q];
            float4 v = *(const float4*)(ef + (size_t)e*4096 + (size_t)c4*4);
            s.x += v.x; s.y += v.y; s.z += v.z; s.w += v.w;
        }
        float4 b = *(const float4*)(b1 + (size_t)c4*4);
        float r[4];
        r[0] = fmaxf(s.x * inv + b.x, 0.f);
        r[1] = fmaxf(s.y * inv + b.y, 0.f);
        r[2] = fmaxf(s.z * inv + b.z, 0.f);
        r[3] = fmaxf(s.w * inv + b.w, 0.f);
        u16x4 h, l;
#pragma unroll
        for (int j = 0; j < 4; j++) {
            unsigned short hh = f2bfu(r[j]);
            h[j] = hh;
            l[j] = f2bfu(r[j] - bfu2f(hh));
        }
        size_t off = (size_t)n*4096 + (size_t)c4*4;
        *(u16x4*)(hHi + off) = h;
        *(u16x4*)(hLo + off) = l;
    }
}

// --------------------------------------------------------------- GEMM2
// gpart[ks][4096][64] partial of h @ w2 ; 64x64 tile, BK=32, K split 8-way.
__global__ __launch_bounds__(256) void gemm2(const unsigned short* __restrict__ Ah,
                                             const unsigned short* __restrict__ Al,
                                             const unsigned short* __restrict__ Bh,
                                             const unsigned short* __restrict__ Bl,
                                             float* __restrict__ gpart) {
    __shared__ __align__(16) unsigned short sAh[64*32], sAl[64*32];
    __shared__ __align__(16) unsigned short sBh[64*32], sBl[64*32];
    int bm = blockIdx.x;            // 64
    int ks = blockIdx.y;            // 8 -> K range 512
    int t = threadIdx.x, lane = t & 63, wid = t >> 6;
    int wr = wid >> 1, wc = wid & 1;
    int ln15 = lane & 15, kq = (lane >> 4) * 8;
    int r = t >> 2, kk = (t & 3) * 8;
    size_t aOff = (size_t)(bm*64 + r) * 4096 + ks * 512 + kk;
    size_t bOff = (size_t)r * 4096 + ks * 512 + kk;   // w2t row r (< 64)
    f32x4 acc[2][2] = {};

    for (int kt = 0; kt < 16; ++kt) {
        int ko = kt * 32;
        GLL16(Ah + aOff + ko, sAh + (size_t)t*8);
        GLL16(Al + aOff + ko, sAl + (size_t)t*8);
        GLL16(Bh + bOff + ko, sBh + (size_t)t*8);
        GLL16(Bl + bOff + ko, sBl + (size_t)t*8);
        asm volatile("s_waitcnt vmcnt(0)" ::: "memory");
        __syncthreads();

        bf16x8 ah[2], al[2], bh[2], bl[2];
#pragma unroll
        for (int m = 0; m < 2; m++) {
            int ro = (wr*32 + m*16 + ln15) * 32 + kq;
            ah[m] = *reinterpret_cast<const bf16x8*>(sAh + ro);
            al[m] = *reinterpret_cast<const bf16x8*>(sAl + ro);
        }
#pragma unroll
        for (int n = 0; n < 2; n++) {
            int ro = (wc*32 + n*16 + ln15) * 32 + kq;
            bh[n] = *reinterpret_cast<const bf16x8*>(sBh + ro);
            bl[n] = *reinterpret_cast<const bf16x8*>(sBl + ro);
        }
#pragma unroll
        for (int m = 0; m < 2; m++)
#pragma unroll
            for (int n = 0; n < 2; n++) {
                acc[m][n] = __builtin_amdgcn_mfma_f32_16x16x32_bf16(ah[m], bh[n], acc[m][n], 0, 0, 0);
                acc[m][n] = __builtin_amdgcn_mfma_f32_16x16x32_bf16(ah[m], bl[n], acc[m][n], 0, 0, 0);
                acc[m][n] = __builtin_amdgcn_mfma_f32_16x16x32_bf16(al[m], bh[n], acc[m][n], 0, 0, 0);
            }
        __syncthreads();
    }

    float* outp = gpart + (size_t)ks * (4096 * 64);
#pragma unroll
    for (int m = 0; m < 2; m++) {
        int rb = bm*64 + wr*32 + m*16 + (lane >> 4) * 4;
#pragma unroll
        for (int n = 0; n < 2; n++) {
            int cb = wc*32 + n*16 + ln15;
#pragma unroll
            for (int j = 0; j < 4; j++)
                outp[(size_t)(rb + j) * 64 + cb] = acc[m][n][j];
        }
    }
}

// -------------------------------------------------- conv2 aggregation + tanh
__global__ __launch_bounds__(256) void ef2k(const float* __restrict__ gpart,
                                            const int* __restrict__ members,
                                            float* __restrict__ ef2) {
    int e = blockIdx.x * 4 + (threadIdx.x >> 6);
    int c = threadIdx.x & 63;
    float s = 0.f;
#pragma unroll
    for (int k = 0; k < 8; k++) {
        int m = members[e*8 + k];
        float g = 0.f;
#pragma unroll
        for (int p = 0; p < 8; p++) g += gpart[(size_t)p * (4096*64) + (size_t)m*64 + c];
        s += g;
    }
    ef2[e*64 + c] = s * 0.125f;
}

__global__ __launch_bounds__(256) void agg2k(const float* __restrict__ ef2,
                                             const int* __restrict__ offs,
                                             const int* __restrict__ deg,
                                             const int* __restrict__ list,
                                             const float* __restrict__ b2,
                                             float* __restrict__ out) {
    int n = blockIdx.x * 4 + (threadIdx.x >> 6);
    int c = threadIdx.x & 63;
    int d = deg[n], o = offs[n];
    float inv = d > 0 ? 1.0f / (float)d : 0.0f;
    float s = 0.f;
    for (int q = 0; q < d; q++) s += ef2[list[o + q] * 64 + c];
    out[(size_t)n*64 + c] = tanhf(s * inv + b2[c]);
}

// ------------------------------------------------------------------ launcher
extern "C" void kernel_launch(void* const* d_in, const int* in_sizes, int n_in,
                              void* d_out, int out_size, void* d_ws, size_t ws_size,
                              hipStream_t stream) {
    const float* x  = (const float*)d_in[0];
    const float* S  = (const float*)d_in[1];
    const float* w1 = (const float*)d_in[2];
    const float* b1 = (const float*)d_in[3];
    const float* w2 = (const float*)d_in[4];
    const float* b2 = (const float*)d_in[5];
    float* out = (float*)d_out;

    char* p = (char*)d_ws;
    int* members = (int*)(p);                         // 128 KB
    int* deg     = (int*)(p + 0x020000);              // 16 KB
    int* cursor  = (int*)(p + 0x024000);              // 16 KB
    int* offs    = (int*)(p + 0x028000);              // 16.4 KB
    int* list    = (int*)(p + 0x030000);              // 128 KB
    unsigned short* w2t_hi = (unsigned short*)(p + 0x050000);  // 512 KB
    unsigned short* w2t_lo = (unsigned short*)(p + 0x0D0000);  // 512 KB
    float* ef2b    = (float*)(p + 0x150000);          // 1 MB
    float* gpart   = (float*)(p + 0x400000);          // 8 MB
    unsigned short* x_hi   = (unsigned short*)(p + 0x1000000); // 32 MB
    unsigned short* x_lo   = x_hi   + (1u << 24);
    unsigned short* w1t_hi = x_lo   + (1u << 24);
    unsigned short* w1t_lo = w1t_hi + (1u << 24);
    float* xw      = (float*)(w1t_lo + (1u << 24));   // 64 MB -> total 0xD000000 (~208 MB)
    float* ef1     = (float*)w1t_hi;                  // reuse after GEMM1
    unsigned short* h_hi = x_hi;                      // reuse after GEMM1
    unsigned short* h_lo = x_lo;

    hipMemsetAsync(p + 0x020000, 0, 0x8000, stream);  // zero deg + cursor

    topk8   <<<4096, 256, 0, stream>>>(S, members, deg);
    scan4096<<<1, 1024, 0, stream>>>(deg, offs);
    csrfill <<<128, 256, 0, stream>>>(members, offs, cursor, list);
    csrsort <<<16, 256, 0, stream>>>(offs, deg, list);

    splitk  <<<4096, 256, 0, stream>>>(x, x_hi, x_lo, 4194304);
    tsplit  <<<dim3(64, 64), 256, 0, stream>>>(w1, w1t_hi, w1t_lo, 4096, 4096);
    tsplit  <<<dim3(1, 64),  256, 0, stream>>>(w2, w2t_hi, w2t_lo, 4096, 64);

    gemm1   <<<256, 512, 0, stream>>>(x_hi, x_lo, w1t_hi, w1t_lo, xw);

    edgefeat1<<<4096, 256, 0, stream>>>(xw, members, ef1);
    agg1    <<<4096, 256, 0, stream>>>(ef1, offs, deg, list, b1, h_hi, h_lo);

    gemm2   <<<dim3(64, 8), 256, 0, stream>>>(h_hi, h_lo, w2t_hi, w2t_lo, gpart);
    ef2k    <<<1024, 256, 0, stream>>>(gpart, members, ef2b);
    agg2k   <<<1024, 256, 0, stream>>>(ef2b, offs, deg, list, b2, out);
}

// Round 11
// 787.978 us; speedup vs baseline: 1.2777x; 1.0975x over previous
//
#include <hip/hip_runtime.h>
#include <hip/hip_bf16.h>

// NetHY: kNN-hypergraph 2-layer conv on MI355X (gfx950)
// R9..R11: tail restructure around linearity: agg(x@w1) == agg(x)@w1.
//  - aggregate x FIRST (fill_ef+agg1x), split fused into agg1x -> splitk gone
//  - gemm1 epilogue fuses +b1, relu, bf16 hi/lo split (writes h directly)
//  - csrsort dropped (atomic order only perturbs fp32 rounding ~1e-7)
//  - launches merged: {topk8,tsplit w1,tsplit w2} -> prep; {csrfill,edgefeat1x} -> one
//  gemm1 K-loop is R8-verbatim (367 us, 0 conflicts, MfmaUtil 49%).
// Workspace requirement: ~208 MB (0xD000000 bytes).

typedef __bf16 bf16x8 __attribute__((ext_vector_type(8)));
typedef float  f32x4  __attribute__((ext_vector_type(4)));
typedef unsigned short u16x4 __attribute__((ext_vector_type(4)));

#define GLL16(gp, lp) __builtin_amdgcn_global_load_lds( \
    (const __attribute__((address_space(1))) void*)(gp), \
    (__attribute__((address_space(3))) void*)(lp), 16, 0, 0)

__device__ __forceinline__ unsigned short f2bfu(float f) {
    unsigned int u = __float_as_uint(f);
    unsigned int r = (u + 0x7FFFu + ((u >> 16) & 1u)) >> 16;   // RNE, no NaN in data
    return (unsigned short)r;
}
__device__ __forceinline__ float bfu2f(unsigned short s) {
    return __uint_as_float(((unsigned int)s) << 16);
}

// ------------------------------------------------ prep: topk8 + tsplit w1/w2
__device__ __forceinline__ void topk8_body(const float* __restrict__ S,
                                           int* __restrict__ members,
                                           int* __restrict__ deg,
                                           int row, char* smem) {
    float* sv = (float*)smem;                 // [2][2048]
    int*   si = (int*)(smem + 16384);         // [2][2048]
    int t = threadIdx.x;
    const float* Sr = S + (size_t)row * 4096;
    float v[8]; int ix[8];
#pragma unroll
    for (int i = 0; i < 8; i++) { v[i] = -3.402823466e38f; ix[i] = 0x7FFFFFFF; }
    for (int j = t; j < 4096; j += 256) {
        float x = Sr[j];
        if (x > v[7]) {                    // strict: equal keeps earlier (smaller) index
            v[7] = x; ix[7] = j;
#pragma unroll
            for (int i = 7; i > 0; i--) {
                if (v[i] > v[i-1]) {
                    float tv = v[i]; v[i] = v[i-1]; v[i-1] = tv;
                    int   ti = ix[i]; ix[i] = ix[i-1]; ix[i-1] = ti;
                }
            }
        }
    }
#pragma unroll
    for (int i = 0; i < 8; i++) { sv[t*8+i] = v[i]; si[t*8+i] = ix[i]; }
    __syncthreads();
    int cur = 0;
    for (int half = 128; half >= 1; half >>= 1) {
        if (t < half) {
            const float* av = &sv[cur*2048 + t*8];        const int* ai = &si[cur*2048 + t*8];
            const float* bv = &sv[cur*2048 + (t+half)*8]; const int* bi = &si[cur*2048 + (t+half)*8];
            float* ov = &sv[(cur^1)*2048 + t*8];          int* oi = &si[(cur^1)*2048 + t*8];
            int pa = 0, pb = 0;
#pragma unroll
            for (int r = 0; r < 8; r++) {
                float va = av[pa], vb = bv[pb];
                int   ia = ai[pa], ib = bi[pb];
                bool ta = (va > vb) || (va == vb && ia < ib);
                if (ta) { ov[r] = va; oi[r] = ia; pa++; }
                else    { ov[r] = vb; oi[r] = ib; pb++; }
            }
        }
        __syncthreads();
        cur ^= 1;
    }
    if (t < 8) {
        int idx = si[cur*2048 + t];
        members[row*8 + t] = idx;
        atomicAdd(&deg[idx], 1);
    }
}

__device__ __forceinline__ void tsplit_body(const float* __restrict__ in,
                                            unsigned short* __restrict__ oh,
                                            unsigned short* __restrict__ ol,
                                            int R, int C, int bx, int by, char* smem) {
    float* tile = (float*)smem;               // [64][65]
    int c0 = bx * 64, r0 = by * 64;
    int tx = threadIdx.x & 63, ty = threadIdx.x >> 6;   // 64 x 4
#pragma unroll
    for (int i = 0; i < 16; i++) {
        int r = i * 4 + ty;
        tile[r*65 + tx] = in[(size_t)(r0 + r) * C + c0 + tx];
    }
    __syncthreads();
#pragma unroll
    for (int i = 0; i < 16; i++) {
        int c = i * 4 + ty;                      // output-local row = input col
        float v = tile[tx*65 + c];
        unsigned short hh = f2bfu(v);
        size_t o = (size_t)(c0 + c) * R + r0 + tx;
        oh[o] = hh;
        ol[o] = f2bfu(v - bfu2f(hh));
    }
}

__global__ __launch_bounds__(256) void prep(const float* __restrict__ S,
                                            int* __restrict__ members,
                                            int* __restrict__ deg,
                                            const float* __restrict__ w1,
                                            unsigned short* __restrict__ w1t_hi,
                                            unsigned short* __restrict__ w1t_lo,
                                            const float* __restrict__ w2,
                                            unsigned short* __restrict__ w2t_hi,
                                            unsigned short* __restrict__ w2t_lo) {
    __shared__ __align__(16) char smem[33024];   // topk: 32KB ; tsplit: 16.6KB
    int bid = blockIdx.x;
    if (bid < 4096) {
        topk8_body(S, members, deg, bid, smem);
    } else if (bid < 8192) {
        int b = bid - 4096;
        tsplit_body(w1, w1t_hi, w1t_lo, 4096, 4096, b & 63, b >> 6, smem);
    } else {
        tsplit_body(w2, w2t_hi, w2t_lo, 4096, 64, 0, bid - 8192, smem);
    }
}

// ------------------------------------------------------------- CSR scan
__global__ __launch_bounds__(1024) void scan4096(const int* __restrict__ deg,
                                                 int* __restrict__ offs) {
    __shared__ int ts[1024];
    int t = threadIdx.x;
    int a0 = deg[t*4], a1 = deg[t*4+1], a2 = deg[t*4+2], a3 = deg[t*4+3];
    int s = a0 + a1 + a2 + a3;
    ts[t] = s; __syncthreads();
    for (int off = 1; off < 1024; off <<= 1) {
        int v = (t >= off) ? ts[t - off] : 0;
        __syncthreads();
        ts[t] += v;
        __syncthreads();
    }
    int excl = ts[t] - s;
    offs[t*4]   = excl;
    offs[t*4+1] = excl + a0;
    offs[t*4+2] = excl + a0 + a1;
    offs[t*4+3] = excl + a0 + a1 + a2;
    if (t == 1023) offs[4096] = ts[t];
}

// ---------------------------- csrfill + edge-mean on x (merged, independent)
__global__ __launch_bounds__(256) void fill_ef(const int* __restrict__ members,
                                               const int* __restrict__ offs,
                                               int* __restrict__ cursor,
                                               int* __restrict__ list,
                                               const float* __restrict__ x,
                                               float* __restrict__ ef) {
    int bid = blockIdx.x;
    if (bid < 128) {
        int i = bid * 256 + threadIdx.x;   // 32768
        int n = members[i];
        int pos = atomicAdd(&cursor[n], 1);
        list[offs[n] + pos] = i >> 3;      // edge id (order irrelevant: fp32 sum)
        return;
    }
    int e = bid - 128, t = threadIdx.x;
    int m[8];
#pragma unroll
    for (int k = 0; k < 8; k++) m[k] = members[e*8 + k];
#pragma unroll
    for (int it = 0; it < 4; ++it) {
        int c4 = t + it * 256;
        float4 s = {0.f, 0.f, 0.f, 0.f};
#pragma unroll
        for (int k = 0; k < 8; k++) {
            float4 v = *(const float4*)(x + (size_t)m[k]*4096 + (size_t)c4*4);
            s.x += v.x; s.y += v.y; s.z += v.z; s.w += v.w;
        }
        s.x *= 0.125f; s.y *= 0.125f; s.z *= 0.125f; s.w *= 0.125f;
        *(float4*)(ef + (size_t)e*4096 + (size_t)c4*4) = s;
    }
}

// ------------------------- node-mean of edge feats -> xa (bf16 hi/lo fused)
__global__ __launch_bounds__(256) void agg1x(const float* __restrict__ ef,
                                             const int* __restrict__ offs,
                                             const int* __restrict__ deg,
                                             const int* __restrict__ list,
                                             unsigned short* __restrict__ xaHi,
                                             unsigned short* __restrict__ xaLo) {
    int n = blockIdx.x, t = threadIdx.x;
    int d = deg[n], o = offs[n];
    float inv = d > 0 ? 1.0f / (float)d : 0.0f;
#pragma unroll
    for (int it = 0; it < 4; ++it) {
        int c4 = t + it * 256;
        float4 s = {0.f, 0.f, 0.f, 0.f};
        for (int q = 0; q < d; q++) {
            int e = list[o + q];
            float4 v = *(const float4*)(ef + (size_t)e*4096 + (size_t)c4*4);
            s.x += v.x; s.y += v.y; s.z += v.z; s.w += v.w;
        }
        float r[4] = {s.x * inv, s.y * inv, s.z * inv, s.w * inv};
        u16x4 h, l;
#pragma unroll
        for (int j = 0; j < 4; j++) {
            unsigned short hh = f2bfu(r[j]);
            h[j] = hh;
            l[j] = f2bfu(r[j] - bfu2f(hh));
        }
        size_t off = (size_t)n*4096 + (size_t)c4*4;
        *(u16x4*)(xaHi + off) = h;
        *(u16x4*)(xaLo + off) = l;
    }
}

// --------------------------------------------------------------- GEMM1
// h = relu(xa @ w1 + b1), 3-term bf16 hi/lo split, written as bf16 hi/lo.
// K-loop = R8 verbatim: 256x256 tile, BK=32, 512 thr (8 waves 2x4),
// double-buffered 128KB LDS, 4-phase interleave, depth-2 vmcnt(8), XOR swizzle.
__global__ __launch_bounds__(512, 2) void gemm1(const unsigned short* __restrict__ Ah,
                                                const unsigned short* __restrict__ Al,
                                                const unsigned short* __restrict__ Bh,
                                                const unsigned short* __restrict__ Bl,
                                                const float* __restrict__ b1,
                                                unsigned short* __restrict__ hHi,
                                                unsigned short* __restrict__ hLo) {
    // [buf][tensor: Ah,Al,Bh,Bl][256 rows][32 k] shorts ; 128 KB total
    __shared__ __align__(16) unsigned short sm[2 * 4 * 8192];

    const int t = threadIdx.x, lane = t & 63, wid = t >> 6;
    const int wr = wid >> 2, wc = wid & 3;          // wave grid 2x4
    const int ln15 = lane & 15;

    const int bid = blockIdx.x;                     // 256 = 16x16 tiles
    const int swz = (bid & 7) * 32 + (bid >> 3);    // 32 consecutive per XCD
    const int bm = swz >> 4, bn = swz & 15;

    // ---- staging: wave wid stages chunks {2wid, 2wid+1} (16 rows x 32k each)
    // global k-chunk pre-swizzled per lane (involution matches the read side)
    const int kc8 = (((lane & 3) ^ ((lane >> 3) & 3))) * 8;
    const unsigned rA0 = (unsigned)(bm * 256 + wid * 32 + (lane >> 2));
    const unsigned rB0 = (unsigned)(bn * 256 + wid * 32 + (lane >> 2));
    const unsigned oA0 = rA0 * 4096u + (unsigned)kc8, oA1 = oA0 + 16u * 4096u;
    const unsigned oB0 = rB0 * 4096u + (unsigned)kc8, oB1 = oB0 + 16u * 4096u;
    const int dls = wid * 1024;                     // chunk c0 dst (shorts)

#define STAGE1(kt, buf) {                                              \
    const int bb_ = (buf) * 32768; const unsigned ko_ = (kt) * 32u;    \
    GLL16(Ah + oA0 + ko_, &sm[bb_ + 0*8192 + dls]);                    \
    GLL16(Ah + oA1 + ko_, &sm[bb_ + 0*8192 + dls + 512]);              \
    GLL16(Al + oA0 + ko_, &sm[bb_ + 1*8192 + dls]);                    \
    GLL16(Al + oA1 + ko_, &sm[bb_ + 1*8192 + dls + 512]);              \
    GLL16(Bh + oB0 + ko_, &sm[bb_ + 2*8192 + dls]);                    \
    GLL16(Bh + oB1 + ko_, &sm[bb_ + 2*8192 + dls + 512]);              \
    GLL16(Bl + oB0 + ko_, &sm[bb_ + 3*8192 + dls]);                    \
    GLL16(Bl + oB1 + ko_, &sm[bb_ + 3*8192 + dls + 512]); }

    // ---- ds_read side: swizzled slot, lane-constant
    const int soff = ((lane >> 4) ^ ((lane >> 1) & 3)) * 8;  // shorts
    const int arow = (wr * 128 + ln15) * 32 + soff;
    const int brow = (wc * 64  + ln15) * 32 + soff;

#define LDF(bb, T, base, idx) \
    (*reinterpret_cast<const bf16x8*>(&sm[(bb) + (T)*8192 + (base) + (idx)*512]))

    f32x4 acc[8][4] = {};
    bf16x8 ah[4], al[4], bh[4], bl[4];

    STAGE1(0, 0);
    STAGE1(1, 1);

    for (int kt = 0; kt < 128; ++kt) {
        const int bb = (kt & 1) * 32768;
        if (kt < 127) { asm volatile("s_waitcnt vmcnt(8)" ::: "memory"); }
        else          { asm volatile("s_waitcnt vmcnt(0)" ::: "memory"); }
        __builtin_amdgcn_s_barrier();

        // ---- phase 0: read a[0-3], b[0-1]; mfma m0-3 x n0-1
#pragma unroll
        for (int m = 0; m < 4; m++) { ah[m] = LDF(bb, 0, arow, m); al[m] = LDF(bb, 1, arow, m); }
#pragma unroll
        for (int n = 0; n < 2; n++) { bh[n] = LDF(bb, 2, brow, n); bl[n] = LDF(bb, 3, brow, n); }
        __builtin_amdgcn_s_barrier();
        asm volatile("s_waitcnt lgkmcnt(0)" ::: "memory");
        __builtin_amdgcn_sched_barrier(0);
        __builtin_amdgcn_s_setprio(1);
#pragma unroll
        for (int m = 0; m < 4; m++)
#pragma unroll
            for (int n = 0; n < 2; n++) {
                acc[m][n] = __builtin_amdgcn_mfma_f32_16x16x32_bf16(ah[m], bh[n], acc[m][n], 0, 0, 0);
                acc[m][n] = __builtin_amdgcn_mfma_f32_16x16x32_bf16(ah[m], bl[n], acc[m][n], 0, 0, 0);
                acc[m][n] = __builtin_amdgcn_mfma_f32_16x16x32_bf16(al[m], bh[n], acc[m][n], 0, 0, 0);
            }
        __builtin_amdgcn_s_setprio(0);
        __builtin_amdgcn_s_barrier();

        // ---- phase 1: read b[2-3]; mfma m0-3 x n2-3
#pragma unroll
        for (int n = 2; n < 4; n++) { bh[n] = LDF(bb, 2, brow, n); bl[n] = LDF(bb, 3, brow, n); }
        __builtin_amdgcn_s_barrier();
        asm volatile("s_waitcnt lgkmcnt(0)" ::: "memory");
        __builtin_amdgcn_sched_barrier(0);
        __builtin_amdgcn_s_setprio(1);
#pragma unroll
        for (int m = 0; m < 4; m++)
#pragma unroll
            for (int n = 2; n < 4; n++) {
                acc[m][n] = __builtin_amdgcn_mfma_f32_16x16x32_bf16(ah[m], bh[n], acc[m][n], 0, 0, 0);
                acc[m][n] = __builtin_amdgcn_mfma_f32_16x16x32_bf16(ah[m], bl[n], acc[m][n], 0, 0, 0);
                acc[m][n] = __builtin_amdgcn_mfma_f32_16x16x32_bf16(al[m], bh[n], acc[m][n], 0, 0, 0);
            }
        __builtin_amdgcn_s_setprio(0);
        __builtin_amdgcn_s_barrier();

        // ---- phase 2: read a[4-7]; mfma m4-7 x n0-1
#pragma unroll
        for (int m = 0; m < 4; m++) { ah[m] = LDF(bb, 0, arow, m + 4); al[m] = LDF(bb, 1, arow, m + 4); }
        __builtin_amdgcn_s_barrier();
        asm volatile("s_waitcnt lgkmcnt(0)" ::: "memory");
        __builtin_amdgcn_sched_barrier(0);
        __builtin_amdgcn_s_setprio(1);
#pragma unroll
        for (int m = 0; m < 4; m++)
#pragma unroll
            for (int n = 0; n < 2; n++) {
                acc[m+4][n] = __builtin_amdgcn_mfma_f32_16x16x32_bf16(ah[m], bh[n], acc[m+4][n], 0, 0, 0);
                acc[m+4][n] = __builtin_amdgcn_mfma_f32_16x16x32_bf16(ah[m], bl[n], acc[m+4][n], 0, 0, 0);
                acc[m+4][n] = __builtin_amdgcn_mfma_f32_16x16x32_bf16(al[m], bh[n], acc[m+4][n], 0, 0, 0);
            }
        __builtin_amdgcn_s_setprio(0);
        __builtin_amdgcn_s_barrier();

        // ---- phase 3: mfma m4-7 x n2-3 (register-only)
        __builtin_amdgcn_s_setprio(1);
#pragma unroll
        for (int m = 0; m < 4; m++)
#pragma unroll
            for (int n = 2; n < 4; n++) {
                acc[m+4][n] = __builtin_amdgcn_mfma_f32_16x16x32_bf16(ah[m], bh[n], acc[m+4][n], 0, 0, 0);
                acc[m+4][n] = __builtin_amdgcn_mfma_f32_16x16x32_bf16(ah[m], bl[n], acc[m+4][n], 0, 0, 0);
                acc[m+4][n] = __builtin_amdgcn_mfma_f32_16x16x32_bf16(al[m], bh[n], acc[m+4][n], 0, 0, 0);
            }
        __builtin_amdgcn_s_setprio(0);

        // ---- depth-2 prefetch: stage tile kt+2 into the buffer just freed
        if (kt + 2 < 128) STAGE1(kt + 2, kt & 1);
    }

    // ---- epilogue: fused +b1, relu, bf16 hi/lo split
#pragma unroll
    for (int m = 0; m < 8; m++) {
        int rb = bm * 256 + wr * 128 + m * 16 + (lane >> 4) * 4;
#pragma unroll
        for (int n = 0; n < 4; n++) {
            int cb = bn * 256 + wc * 64 + n * 16 + ln15;
            float bias = b1[cb];
#pragma unroll
            for (int j = 0; j < 4; j++) {
                float r = fmaxf(acc[m][n][j] + bias, 0.f);
                unsigned short hh = f2bfu(r);
                size_t o = (size_t)(rb + j) * 4096 + cb;
                hHi[o] = hh;
                hLo[o] = f2bfu(r - bfu2f(hh));
            }
        }
    }
#undef STAGE1
#undef LDF
}

// --------------------------------------------------------------- GEMM2
// gpart[ks][4096][64] partial of h @ w2 ; 64x64 tile, BK=32, K split 8-way.
__global__ __launch_bounds__(256) void gemm2(const unsigned short* __restrict__ Ah,
                                             const unsigned short* __restrict__ Al,
                                             const unsigned short* __restrict__ Bh,
                                             const unsigned short* __restrict__ Bl,
                                             float* __restrict__ gpart) {
    __shared__ __align__(16) unsigned short sAh[64*32], sAl[64*32];
    __shared__ __align__(16) unsigned short sBh[64*32], sBl[64*32];
    int bm = blockIdx.x;            // 64
    int ks = blockIdx.y;            // 8 -> K range 512
    int t = threadIdx.x, lane = t & 63, wid = t >> 6;
    int wr = wid >> 1, wc = wid & 1;
    int ln15 = lane & 15, kq = (lane >> 4) * 8;
    int r = t >> 2, kk = (t & 3) * 8;
    size_t aOff = (size_t)(bm*64 + r) * 4096 + ks * 512 + kk;
    size_t bOff = (size_t)r * 4096 + ks * 512 + kk;   // w2t row r (< 64)
    f32x4 acc[2][2] = {};

    for (int kt = 0; kt < 16; ++kt) {
        int ko = kt * 32;
        GLL16(Ah + aOff + ko, sAh + (size_t)t*8);
        GLL16(Al + aOff + ko, sAl + (size_t)t*8);
        GLL16(Bh + bOff + ko, sBh + (size_t)t*8);
        GLL16(Bl + bOff + ko, sBl + (size_t)t*8);
        asm volatile("s_waitcnt vmcnt(0)" ::: "memory");
        __syncthreads();

        bf16x8 ah[2], al[2], bh[2], bl[2];
#pragma unroll
        for (int m = 0; m < 2; m++) {
            int ro = (wr*32 + m*16 + ln15) * 32 + kq;
            ah[m] = *reinterpret_cast<const bf16x8*>(sAh + ro);
            al[m] = *reinterpret_cast<const bf16x8*>(sAl + ro);
        }
#pragma unroll
        for (int n = 0; n < 2; n++) {
            int ro = (wc*32 + n*16 + ln15) * 32 + kq;
            bh[n] = *reinterpret_cast<const bf16x8*>(sBh + ro);
            bl[n] = *reinterpret_cast<const bf16x8*>(sBl + ro);
        }
#pragma unroll
        for (int m = 0; m < 2; m++)
#pragma unroll
            for (int n = 0; n < 2; n++) {
                acc[m][n] = __builtin_amdgcn_mfma_f32_16x16x32_bf16(ah[m], bh[n], acc[m][n], 0, 0, 0);
                acc[m][n] = __builtin_amdgcn_mfma_f32_16x16x32_bf16(ah[m], bl[n], acc[m][n], 0, 0, 0);
                acc[m][n] = __builtin_amdgcn_mfma_f32_16x16x32_bf16(al[m], bh[n], acc[m][n], 0, 0, 0);
            }
        __syncthreads();
    }

    float* outp = gpart + (size_t)ks * (4096 * 64);
#pragma unroll
    for (int m = 0; m < 2; m++) {
        int rb = bm*64 + wr*32 + m*16 + (lane >> 4) * 4;
#pragma unroll
        for (int n = 0; n < 2; n++) {
            int cb = wc*32 + n*16 + ln15;
#pragma unroll
            for (int j = 0; j < 4; j++)
                outp[(size_t)(rb + j) * 64 + cb] = acc[m][n][j];
        }
    }
}

// -------------------------------------------------- conv2 aggregation + tanh
__global__ __launch_bounds__(256) void ef2k(const float* __restrict__ gpart,
                                            const int* __restrict__ members,
                                            float* __restrict__ ef2) {
    int e = blockIdx.x * 4 + (threadIdx.x >> 6);
    int c = threadIdx.x & 63;
    float s = 0.f;
#pragma unroll
    for (int k = 0; k < 8; k++) {
        int m = members[e*8 + k];
        float g = 0.f;
#pragma unroll
        for (int p = 0; p < 8; p++) g += gpart[(size_t)p * (4096*64) + (size_t)m*64 + c];
        s += g;
    }
    ef2[e*64 + c] = s * 0.125f;
}

__global__ __launch_bounds__(256) void agg2k(const float* __restrict__ ef2,
                                             const int* __restrict__ offs,
                                             const int* __restrict__ deg,
                                             const int* __restrict__ list,
                                             const float* __restrict__ b2,
                                             float* __restrict__ out) {
    int n = blockIdx.x * 4 + (threadIdx.x >> 6);
    int c = threadIdx.x & 63;
    int d = deg[n], o = offs[n];
    float inv = d > 0 ? 1.0f / (float)d : 0.0f;
    float s = 0.f;
    for (int q = 0; q < d; q++) s += ef2[list[o + q] * 64 + c];
    out[(size_t)n*64 + c] = tanhf(s * inv + b2[c]);
}

// ------------------------------------------------------------------ launcher
extern "C" void kernel_launch(void* const* d_in, const int* in_sizes, int n_in,
                              void* d_out, int out_size, void* d_ws, size_t ws_size,
                              hipStream_t stream) {
    const float* x  = (const float*)d_in[0];
    const float* S  = (const float*)d_in[1];
    const float* w1 = (const float*)d_in[2];
    const float* b1 = (const float*)d_in[3];
    const float* w2 = (const float*)d_in[4];
    const float* b2 = (const float*)d_in[5];
    float* out = (float*)d_out;

    char* p = (char*)d_ws;
    int* members = (int*)(p);                         // 128 KB
    int* deg     = (int*)(p + 0x020000);              // 16 KB
    int* cursor  = (int*)(p + 0x024000);              // 16 KB
    int* offs    = (int*)(p + 0x028000);              // 16.4 KB
    int* list    = (int*)(p + 0x030000);              // 128 KB
    unsigned short* w2t_hi = (unsigned short*)(p + 0x050000);  // 512 KB
    unsigned short* w2t_lo = (unsigned short*)(p + 0x0D0000);  // 512 KB
    float* ef2b    = (float*)(p + 0x150000);          // 1 MB
    float* gpart   = (float*)(p + 0x400000);          // 8 MB
    unsigned short* xa_hi  = (unsigned short*)(p + 0x1000000); // 32 MB
    unsigned short* xa_lo  = xa_hi  + (1u << 24);              // 32 MB
    unsigned short* w1t_hi = xa_lo  + (1u << 24);              // 32 MB
    unsigned short* w1t_lo = w1t_hi + (1u << 24);              // 32 MB
    float* ef_x    = (float*)(w1t_lo + (1u << 24));   // 64 MB (region X)
    unsigned short* h_hi = (unsigned short*)ef_x;     // reuse X after agg1x
    unsigned short* h_lo = h_hi + (1u << 24);         // -> total 0xD000000

    hipMemsetAsync(p + 0x020000, 0, 0x8000, stream);  // zero deg + cursor

    prep    <<<8256, 256, 0, stream>>>(S, members, deg, w1, w1t_hi, w1t_lo,
                                       w2, w2t_hi, w2t_lo);
    scan4096<<<1, 1024, 0, stream>>>(deg, offs);
    fill_ef <<<4224, 256, 0, stream>>>(members, offs, cursor, list, x, ef_x);
    agg1x   <<<4096, 256, 0, stream>>>(ef_x, offs, deg, list, xa_hi, xa_lo);

    gemm1   <<<256, 512, 0, stream>>>(xa_hi, xa_lo, w1t_hi, w1t_lo, b1, h_hi, h_lo);

    gemm2   <<<dim3(64, 8), 256, 0, stream>>>(h_hi, h_lo, w2t_hi, w2t_lo, gpart);
    ef2k    <<<1024, 256, 0, stream>>>(gpart, members, ef2b);
    agg2k   <<<1024, 256, 0, stream>>>(ef2b, offs, deg, list, b2, out);
}